// Round 16
// baseline (478.086 us; speedup 1.0000x reference)
//
#include <hip/hip_runtime.h>
#include <hip/hip_fp16.h>

#define DD 48
#define HW (48 * 48)
#define NV (48 * 48 * 48)   // 110592 voxels
#define COUT 32

// deform tile geometry
#define TD 4
#define TH 8
#define TW 8
#define RD (TD + 4)         // 8   (halo +-2)
#define RH (TH + 4)         // 12
#define RW (TW + 4)         // 12
#define REGN (RD * RH * RW) // 1152 positions per channel
#define NCHC 16             // channels staged per chunk (8 __half2 pairs)

typedef _Float16 h16;
typedef __attribute__((ext_vector_type(8))) short bf16x8;
typedef __attribute__((ext_vector_type(4))) float f32x4;
typedef __attribute__((ext_vector_type(2))) float f32x2;
typedef __attribute__((ext_vector_type(4))) int i32x4;

__device__ __forceinline__ unsigned int bf16rne(float f) {
    unsigned int u = __builtin_bit_cast(unsigned int, f);
    return (u + 0x7FFFu + ((u >> 16) & 1u)) >> 16;
}
__device__ __forceinline__ float h16f(unsigned short u) {
    return (float)__builtin_bit_cast(h16, u);
}

// ---------------------------------------------------------------------------
// W_pre for the MFMA offset conv: bf16 [m=96][kpad], k = tap*CIN + ci.
// ---------------------------------------------------------------------------
template <int CIN>
__global__ __launch_bounds__(256) void make_wpre_kernel(
    const float* __restrict__ w, unsigned short* __restrict__ Wp)
{
    constexpr int NCHUNK = (CIN == 32) ? 27 : 14;
    constexpr int KPAD = NCHUNK * 32;
    const int i = blockIdx.x * 256 + threadIdx.x;
    if (i >= 96 * KPAD) return;
    const int m = i / KPAD;
    const int kg = i % KPAD;
    const int tap = kg / CIN, ci = kg % CIN;
    float val = 0.f;
    if (m < 81 && tap < 27) val = w[m * (CIN * 27) + ci * 27 + tap];
    Wp[i] = (unsigned short)bf16rne(val);
}

// Weight transpose for scalar deform: wt[co][ci][tap] -> wT[tap][ci][co].
__global__ __launch_bounds__(256) void transpose_w_kernel(
    const float* __restrict__ wt, float* __restrict__ wT, int COUTN, int CIN)
{
    const int i = blockIdx.x * 256 + threadIdx.x;
    const int total = COUTN * CIN * 27;
    if (i >= total) return;
    const int co = i / (CIN * 27);
    const int r = i % (CIN * 27);
    const int ci = r / 27;
    const int tap = r % 27;
    wT[(tap * CIN + ci) * COUTN + co] = wt[i];
}

// ---------------------------------------------------------------------------
// conv_off chunk loader: 16 strided global loads + bf16 pack for K-chunk c.
// Optional inline BN+ReLU (layer-2 reads pre-BN y).
// ---------------------------------------------------------------------------
template <int CIN, bool BN>
__device__ __forceinline__ void conv_off_load(
    const float* __restrict__ x, const float* __restrict__ sc,
    const float* __restrict__ sh, int sd, int shh, int sww, int skh, int c,
    unsigned int pk[8])
{
    const int kg0 = c * 32 + skh * 16;
    const int tap = kg0 / CIN;
    if (tap < 27) {
        const int dz = tap / 9 - 1;
        const int dy = (tap / 3) % 3 - 1;
        const int dx = tap % 3 - 1;
        const int zd = sd + dz, zh = shh + dy, zw = sww + dx;
        const bool ok = ((unsigned)zd < 48u) & ((unsigned)zh < 48u)
                      & ((unsigned)zw < 48u);
        const int gbase = (zd * DD + zh) * DD + zw;
        const int ci0 = kg0 % CIN;
        const float* xb = x + ci0 * NV + gbase;
#pragma unroll
        for (int p = 0; p < 8; ++p) {
            float f0 = ok ? xb[(2 * p) * NV] : 0.f;
            float f1 = ok ? xb[(2 * p + 1) * NV] : 0.f;
            if (BN) {
                f0 = fmaxf(f0 * sc[ci0 + 2 * p] + sh[ci0 + 2 * p], 0.f);
                f1 = fmaxf(f1 * sc[ci0 + 2 * p + 1] + sh[ci0 + 2 * p + 1], 0.f);
                if (!ok) { f0 = 0.f; f1 = 0.f; }
            }
            pk[p] = bf16rne(f0) | (bf16rne(f1) << 16);
        }
    } else {
#pragma unroll
        for (int p = 0; p < 8; ++p) pk[p] = 0u;
    }
}

// ---------------------------------------------------------------------------
// Offset conv as MFMA GEMM (verified since R6; R12 register prefetch).
// Epilogue writes packed AoS offsets off4[tap][v] = {od,oh,ow,pad} h16.
// ---------------------------------------------------------------------------
template <int CIN, bool BN>
__global__ __launch_bounds__(256) void conv_off_mfma_kernel(
    const float* __restrict__ x, const unsigned short* __restrict__ Wp,
    const float* __restrict__ bias, const float* __restrict__ sc,
    const float* __restrict__ sh, unsigned short* __restrict__ off4)
{
    constexpr int NCHUNK = (CIN == 32) ? 27 : 14;
    constexpr int KPAD = NCHUNK * 32;
    __shared__ unsigned int lds[16 * 128];   // 8 KB

    const int t = threadIdx.x;
    const int bxs = (blockIdx.x & 7) * (NV / 128 / 8) + (blockIdx.x >> 3); // XCD swizzle
    const int v0 = bxs * 128;

    const int sn = t >> 1;
    const int skh = t & 1;
    const int sv = v0 + sn;
    const int sd = sv / HW;
    const int shh = (sv / DD) % DD;
    const int sww = sv % DD;

    const int wv = t >> 6;
    const int l = t & 63;
    const int lg = l >> 4;
    const int ln = l & 15;

    const int bw0 = (((2 * wv) * 16 + ln) + 8 * lg) & 127;
    const int bw1 = (((2 * wv + 1) * 16 + ln) + 8 * lg) & 127;
    const int abase = ln * KPAD + lg * 8;

    f32x4 acc[6][2];
#pragma unroll
    for (int r = 0; r < 6; ++r)
#pragma unroll
        for (int nt = 0; nt < 2; ++nt)
            acc[r][nt] = (f32x4){0.f, 0.f, 0.f, 0.f};

    unsigned int pk[8];
    conv_off_load<CIN, BN>(x, sc, sh, sd, shh, sww, skh, 0, pk);

    for (int c = 0; c < NCHUNK; ++c) {
        __syncthreads();   // previous chunk's LDS reads done
#pragma unroll
        for (int p = 0; p < 8; ++p) {
            const int word = (skh * 8 + p) * 128
                           + ((sn + 16 * skh + 8 * (p >> 2)) & 127);
            lds[word] = pk[p];
        }
        __syncthreads();

        // prefetch next chunk into registers (overlaps the MFMAs below)
        unsigned int nk[8];
        if (c + 1 < NCHUNK) {
            conv_off_load<CIN, BN>(x, sc, sh, sd, shh, sww, skh, c + 1, nk);
        } else {
#pragma unroll
            for (int p = 0; p < 8; ++p) nk[p] = 0u;
        }

        const unsigned short* wp = Wp + c * 32 + abase;
#pragma unroll
        for (int r = 0; r < 6; ++r) {
            const bf16x8 a = *(const bf16x8*)(wp + r * 16 * KPAD);
#pragma unroll
            for (int nt = 0; nt < 2; ++nt) {
                const int bw = nt ? bw1 : bw0;
                const int w0 = (int)lds[(4 * lg + 0) * 128 + bw];
                const int w1 = (int)lds[(4 * lg + 1) * 128 + bw];
                const int w2 = (int)lds[(4 * lg + 2) * 128 + bw];
                const int w3 = (int)lds[(4 * lg + 3) * 128 + bw];
                const i32x4 wi = {w0, w1, w2, w3};
                const bf16x8 b = __builtin_bit_cast(bf16x8, wi);
                acc[r][nt] = __builtin_amdgcn_mfma_f32_16x16x32_bf16(a, b, acc[r][nt], 0, 0, 0);
            }
        }

#pragma unroll
        for (int p = 0; p < 8; ++p) pk[p] = nk[p];
    }

    // epilogue: m = axis*27 + tap; write h16 into off4[tap*NV + col] slot axis
#pragma unroll
    for (int r = 0; r < 6; ++r) {
        const int mbase = r * 16 + lg * 4;
#pragma unroll
        for (int j = 0; j < 4; ++j) {
            const int m = mbase + j;
            if (m < 81) {
                const int axis = m / 27;
                const int tap = m - axis * 27;
#pragma unroll
                for (int nt = 0; nt < 2; ++nt) {
                    const int col = v0 + (2 * wv + nt) * 16 + ln;
                    const h16 val = (h16)(acc[r][nt][j] + bias[m]);
                    ((h16*)(off4 + ((size_t)tap * NV + col) * 4))[axis] = val;
                }
            }
        }
    }
}

// ---------------------------------------------------------------------------
// Deformable conv, LDS-tiled, fp16 channel-pair tile (R14-proven).
// R15: NCHC=16 channels per chunk — halves the per-tap coord/off4 redundancy
// (L2: 2 chunks instead of 4; L1: single chunk, writes y DIRECTLY, no
// split-K partials). Contraction stays fp32 pk_fma (exact).
// ---------------------------------------------------------------------------
template <int CIN, bool BN, bool WRITE_Y>
__global__ __launch_bounds__(256) void deform_tile_kernel(
    const float* __restrict__ x, const unsigned short* __restrict__ off4,
    const float* __restrict__ wD, const float* __restrict__ sc,
    const float* __restrict__ sh, float* __restrict__ out)
{
    __shared__ __half2 regs[NCHC / 2][REGN];   // 36864 B

    const int t = threadIdx.x;
    const int bx = (blockIdx.x & 7) * 54 + (blockIdx.x >> 3);  // XCD swizzle (432/8=54)
    const int tilew = bx % 6;
    const int tileh = (bx / 6) % 6;
    const int tiled = bx / 36;
    const int chunk = blockIdx.y;
    const int c0 = chunk * NCHC;

    const int tz = t >> 6, ty = (t >> 3) & 7, tx = t & 7;
    const int d  = tiled * TD + tz;
    const int hh = tileh * TH + ty;
    const int ww = tilew * TW + tx;
    const int v  = (d * DD + hh) * DD + ww;

    const int dlo = tiled * TD - 2;
    const int hlo = tileh * TH - 2;
    const int wlo = tilew * TW - 2;

    // ---- stage x region: NCHC/2 channel-pairs, fp16 packed (optional BN) ----
    for (int i = t; i < (NCHC / 2) * REGN; i += 256) {
        const int p = i / REGN;
        const int r = i % REGN;
        const int rz = r / (RH * RW);
        const int rr = r % (RH * RW);
        const int ry = rr / RW, rx = rr % RW;
        const int gz = min(max(dlo + rz, 0), 47);
        const int gy = min(max(hlo + ry, 0), 47);
        const int gx = min(max(wlo + rx, 0), 47);
        const int gidx = (gz * DD + gy) * DD + gx;
        float s0 = x[(c0 + 2 * p) * NV + gidx];
        float s1 = x[(c0 + 2 * p + 1) * NV + gidx];
        if (BN) {
            s0 = fmaxf(s0 * sc[c0 + 2 * p] + sh[c0 + 2 * p], 0.f);
            s1 = fmaxf(s1 * sc[c0 + 2 * p + 1] + sh[c0 + 2 * p + 1], 0.f);
        }
        regs[p][r] = __floats2half2_rn(s0, s1);
    }
    __syncthreads();

    f32x2 acc2[16];
#pragma unroll
    for (int i = 0; i < 16; ++i) acc2[i] = (f32x2){0.f, 0.f};

    for (int k = 0; k < 27; ++k) {
        const int dz = k / 9 - 1;
        const int dy = (k / 3) % 3 - 1;
        const int dx = k % 3 - 1;

        const ushort4 o4 = ((const ushort4*)off4)[(size_t)k * NV + v];
        const float od = h16f(o4.x);
        const float oh = h16f(o4.y);
        const float ow = h16f(o4.z);

        const float pd = fminf(fmaxf((float)(d + dz) + od, 0.0f), 47.0f);
        const float ph = fminf(fmaxf((float)(hh + dy) + oh, 0.0f), 47.0f);
        const float pw = fminf(fmaxf((float)(ww + dx) + ow, 0.0f), 47.0f);

        const float d0f = floorf(pd), h0f = floorf(ph), w0f = floorf(pw);
        const float fd = pd - d0f, fh = ph - h0f, fw = pw - w0f;
        const int d0 = (int)d0f, h0 = (int)h0f, w0 = (int)w0f;

        const float gd = 1.0f - fd, gh = 1.0f - fh, gw = 1.0f - fw;
        const float c000 = gd * gh * gw, c001 = gd * gh * fw;
        const float c010 = gd * fh * gw, c011 = gd * fh * fw;
        const float c100 = fd * gh * gw, c101 = fd * gh * fw;
        const float c110 = fd * fh * gw, c111 = fd * fh * fw;

        const float* wrow = wD + (k * CIN + c0) * COUT;

        const int ld = d0 - dlo, lh = h0 - hlo, lw = w0 - wlo;
        // fixed-offset reads need ld+1/lh+1/lw+1 in range (clamp => coef 0)
        const bool inreg = (ld >= 0) & (ld <= RD - 2)
                         & (lh >= 0) & (lh <= RH - 2)
                         & (lw >= 0) & (lw <= RW - 2);

        if (inreg) {
            const int base = (ld * RH + lh) * RW + lw;
            const __half2 C000 = __float2half2_rn(c000), C001 = __float2half2_rn(c001);
            const __half2 C010 = __float2half2_rn(c010), C011 = __float2half2_rn(c011);
            const __half2 C100 = __float2half2_rn(c100), C101 = __float2half2_rn(c101);
            const __half2 C110 = __float2half2_rn(c110), C111 = __float2half2_rn(c111);
#pragma unroll
            for (int p = 0; p < NCHC / 2; ++p) {
                const __half2* xc = &regs[p][base];
                __half2 vp = __hmul2(C000, xc[0]);
                vp = __hfma2(C001, xc[1], vp);
                vp = __hfma2(C010, xc[RW], vp);
                vp = __hfma2(C011, xc[RW + 1], vp);
                vp = __hfma2(C100, xc[RH * RW], vp);
                vp = __hfma2(C101, xc[RH * RW + 1], vp);
                vp = __hfma2(C110, xc[RH * RW + RW], vp);
                vp = __hfma2(C111, xc[RH * RW + RW + 1], vp);
                const float v0 = __low2float(vp);
                const float v1 = __high2float(vp);
                const f32x2* wpe = (const f32x2*)(wrow + (2 * p) * COUT);
                const f32x2* wpo = (const f32x2*)(wrow + (2 * p + 1) * COUT);
#pragma unroll
                for (int co = 0; co < 16; ++co)
                    acc2[co] += v0 * wpe[co] + v1 * wpo[co];
            }
        } else {
            const int dst = (d0 < 47) ? 1 : 0;
            const int hst = (h0 < 47) ? 1 : 0;
            const int wst = (w0 < 47) ? 1 : 0;
            const int i000 = (d0 * DD + h0) * DD + w0;
            const int sd2 = dst ? HW : 0, sh2 = hst ? DD : 0, sw2 = wst;
#pragma unroll
            for (int ci = 0; ci < NCHC; ++ci) {
                const float* xc = x + (c0 + ci) * NV + i000;
                float q000 = xc[0],         q001 = xc[sw2];
                float q010 = xc[sh2],       q011 = xc[sh2 + sw2];
                float q100 = xc[sd2],       q101 = xc[sd2 + sw2];
                float q110 = xc[sd2 + sh2], q111 = xc[sd2 + sh2 + sw2];
                if (BN) {
                    const float a = sc[c0 + ci], b = sh[c0 + ci];
                    q000 = fmaxf(q000 * a + b, 0.f); q001 = fmaxf(q001 * a + b, 0.f);
                    q010 = fmaxf(q010 * a + b, 0.f); q011 = fmaxf(q011 * a + b, 0.f);
                    q100 = fmaxf(q100 * a + b, 0.f); q101 = fmaxf(q101 * a + b, 0.f);
                    q110 = fmaxf(q110 * a + b, 0.f); q111 = fmaxf(q111 * a + b, 0.f);
                }
                const float val = q000 * c000 + q001 * c001
                                + q010 * c010 + q011 * c011
                                + q100 * c100 + q101 * c101
                                + q110 * c110 + q111 * c111;
                const f32x2* wp2 = (const f32x2*)(wrow + ci * COUT);
#pragma unroll
                for (int co = 0; co < 16; ++co)
                    acc2[co] += val * wp2[co];
            }
        }
    }

#pragma unroll
    for (int co = 0; co < 16; ++co) {
        const size_t b = WRITE_Y ? 0 : (size_t)chunk * COUT * NV;
        out[b + (2 * co + 0) * (size_t)NV + v] = acc2[co].x;
        out[b + (2 * co + 1) * (size_t)NV + v] = acc2[co].y;
    }
}

// ---------------------------------------------------------------------------
// Fused: sum NC split-K partials -> y, AND accumulate per-block BN partials.
// ---------------------------------------------------------------------------
template <int NC>
__global__ __launch_bounds__(256) void reduce_stats_kernel(
    const float* __restrict__ part, float* __restrict__ y, float* __restrict__ pbuf)
{
    const int i = blockIdx.x * 256 + threadIdx.x;   // float4 index
    const int stride = COUT * NV / 4;
    float4 a = ((const float4*)part)[i];
#pragma unroll
    for (int c = 1; c < NC; ++c) {
        const float4 b = ((const float4*)part)[i + c * stride];
        a.x += b.x; a.y += b.y; a.z += b.z; a.w += b.w;
    }
    ((float4*)y)[i] = a;

    float s  = a.x + a.y + a.z + a.w;
    float s2 = a.x * a.x + a.y * a.y + a.z * a.z + a.w * a.w;
    __shared__ float ls[256], ls2[256];
    ls[threadIdx.x] = s; ls2[threadIdx.x] = s2;
    __syncthreads();
    for (int st = 128; st > 0; st >>= 1) {
        if (threadIdx.x < st) {
            ls[threadIdx.x]  += ls[threadIdx.x + st];
            ls2[threadIdx.x] += ls2[threadIdx.x + st];
        }
        __syncthreads();
    }
    if (threadIdx.x == 0) {
        pbuf[blockIdx.x * 2 + 0] = ls[0];
        pbuf[blockIdx.x * 2 + 1] = ls2[0];
    }
}

// Stats-only pass (L1: deform wrote y directly).
__global__ __launch_bounds__(256) void stats_kernel(
    const float* __restrict__ y, float* __restrict__ pbuf)
{
    const int i = blockIdx.x * 256 + threadIdx.x;   // float4 index
    const float4 a = ((const float4*)y)[i];
    float s  = a.x + a.y + a.z + a.w;
    float s2 = a.x * a.x + a.y * a.y + a.z * a.z + a.w * a.w;
    __shared__ float ls[256], ls2[256];
    ls[threadIdx.x] = s; ls2[threadIdx.x] = s2;
    __syncthreads();
    for (int st = 128; st > 0; st >>= 1) {
        if (threadIdx.x < st) {
            ls[threadIdx.x]  += ls[threadIdx.x + st];
            ls2[threadIdx.x] += ls2[threadIdx.x + st];
        }
        __syncthreads();
    }
    if (threadIdx.x == 0) {
        pbuf[blockIdx.x * 2 + 0] = ls[0];
        pbuf[blockIdx.x * 2 + 1] = ls2[0];
    }
}

// pbuf slot b belongs to channel b/108 (NV = 108*1024).
__global__ __launch_bounds__(64) void bn_stats_final_kernel(
    const float* __restrict__ pbuf, const float* __restrict__ gamma,
    const float* __restrict__ beta, float* __restrict__ sc, float* __restrict__ sh)
{
    const int c = threadIdx.x;
    if (c >= 32) return;
    float s = 0.0f, s2 = 0.0f;
    for (int p = 0; p < 108; ++p) {
        s  += pbuf[(c * 108 + p) * 2 + 0];
        s2 += pbuf[(c * 108 + p) * 2 + 1];
    }
    const float mu = s * (1.0f / NV);
    const float var = s2 * (1.0f / NV) - mu * mu;
    const float inv = rsqrtf(var + 1e-5f);
    sc[c] = gamma[c] * inv;
    sh[c] = beta[c] - mu * gamma[c] * inv;
}

__global__ __launch_bounds__(256) void bn_apply_kernel(
    const float* __restrict__ y, const float* __restrict__ sc,
    const float* __restrict__ sh, float* __restrict__ out)
{
    const int i = blockIdx.x * 256 + threadIdx.x;
    const int c = (i * 4) / NV;
    const float a = sc[c], b = sh[c];
    float4 t = ((const float4*)y)[i];
    t.x = fmaxf(t.x * a + b, 0.0f);
    t.y = fmaxf(t.y * a + b, 0.0f);
    t.z = fmaxf(t.z * a + b, 0.0f);
    t.w = fmaxf(t.w * a + b, 0.0f);
    ((float4*)out)[i] = t;
}

// ---------------------------------------------------------------------------
extern "C" void kernel_launch(void* const* d_in, const int* in_sizes, int n_in,
                              void* d_out, int out_size, void* d_ws, size_t ws_size,
                              hipStream_t stream) {
    (void)in_sizes; (void)n_in; (void)out_size; (void)ws_size;

    const float* x      = (const float*)d_in[0];
    const float* w_off1 = (const float*)d_in[1];
    const float* b_off1 = (const float*)d_in[2];
    const float* w1     = (const float*)d_in[3];
    const float* gamma1 = (const float*)d_in[4];
    const float* beta1  = (const float*)d_in[5];
    const float* w_off2 = (const float*)d_in[6];
    const float* b_off2 = (const float*)d_in[7];
    const float* w2     = (const float*)d_in[8];
    const float* gamma2 = (const float*)d_in[9];
    const float* beta2  = (const float*)d_in[10];

    char* ws = (char*)d_ws;
    unsigned short* off4 = (unsigned short*)ws; ws += (size_t)27 * NV * 4 * sizeof(unsigned short);
    float* y    = (float*)ws;               ws += (size_t)32 * NV * sizeof(float);
    float* y2   = (float*)ws;               ws += (size_t)32 * NV * sizeof(float);
    float* part = (float*)ws;               ws += (size_t)2 * 32 * NV * sizeof(float);
    float* sc   = (float*)ws;               ws += 32 * sizeof(float);
    float* sh   = (float*)ws;               ws += 32 * sizeof(float);
    float* pbuf = (float*)ws;               ws += 3456 * 2 * sizeof(float);
    unsigned short* Wp1 = (unsigned short*)ws; ws += (size_t)96 * 448 * sizeof(unsigned short);
    unsigned short* Wp2 = (unsigned short*)ws; ws += (size_t)96 * 864 * sizeof(unsigned short);
    float* wD1  = (float*)ws;               ws += (size_t)27 * 16 * 32 * sizeof(float);
    float* wD2  = (float*)ws;               ws += (size_t)27 * 32 * 32 * sizeof(float);

    const int nel4 = (COUT * NV) / 4 / 256;   // 3456 blocks (float4 grids)
    const int ntile = 432;                    // 12 * 6 * 6
    const int ngemm = NV / 128;               // 864

    // ---- weight prep (tiny) ----
    make_wpre_kernel<16><<<(96 * 448 + 255) / 256, 256, 0, stream>>>(w_off1, Wp1);
    make_wpre_kernel<32><<<(96 * 864 + 255) / 256, 256, 0, stream>>>(w_off2, Wp2);
    transpose_w_kernel<<<(32 * 16 * 27 + 255) / 256, 256, 0, stream>>>(w1, wD1, 32, 16);
    transpose_w_kernel<<<(32 * 32 * 27 + 255) / 256, 256, 0, stream>>>(w2, wD2, 32, 32);

    // ---- layer 1 (CIN=16: single chunk, deform writes y directly) ----
    conv_off_mfma_kernel<16, false><<<ngemm, 256, 0, stream>>>(x, Wp1, b_off1, nullptr, nullptr, off4);
    deform_tile_kernel<16, false, true><<<dim3(ntile, 1), 256, 0, stream>>>(x, off4, wD1, nullptr, nullptr, y);
    stats_kernel<<<nel4, 256, 0, stream>>>(y, pbuf);
    bn_stats_final_kernel<<<1, 64, 0, stream>>>(pbuf, gamma1, beta1, sc, sh);
    // (no bn_apply: layer-2 kernels apply BN+ReLU inline when reading y)

    // ---- layer 2 (CIN=32: 2 chunks of 16) ----
    conv_off_mfma_kernel<32, true><<<ngemm, 256, 0, stream>>>(y, Wp2, b_off2, sc, sh, off4);
    deform_tile_kernel<32, true, false><<<dim3(ntile, 2), 256, 0, stream>>>(y, off4, wD2, sc, sh, part);
    reduce_stats_kernel<2><<<nel4, 256, 0, stream>>>(part, y2, pbuf);
    bn_stats_final_kernel<<<1, 64, 0, stream>>>(pbuf, gamma2, beta2, sc, sh);
    bn_apply_kernel<<<nel4, 256, 0, stream>>>(y2, sc, sh, (float*)d_out);
}

// Round 17
// 421.270 us; speedup vs baseline: 1.1349x; 1.1349x over previous
//
#include <hip/hip_runtime.h>
#include <hip/hip_fp16.h>

#define DD 48
#define HW (48 * 48)
#define NV (48 * 48 * 48)   // 110592 voxels
#define COUT 32

// deform tile geometry
#define TD 4
#define TH 8
#define TW 8
#define RD (TD + 4)         // 8   (halo +-2)
#define RH (TH + 4)         // 12
#define RW (TW + 4)         // 12
#define REGN (RD * RH * RW) // 1152 positions per channel

typedef _Float16 h16;
typedef __attribute__((ext_vector_type(8))) short bf16x8;
typedef __attribute__((ext_vector_type(4))) float f32x4;
typedef __attribute__((ext_vector_type(2))) float f32x2;
typedef __attribute__((ext_vector_type(4))) int i32x4;

__device__ __forceinline__ unsigned int bf16rne(float f) {
    unsigned int u = __builtin_bit_cast(unsigned int, f);
    return (u + 0x7FFFu + ((u >> 16) & 1u)) >> 16;
}
__device__ __forceinline__ float h16f(unsigned short u) {
    return (float)__builtin_bit_cast(h16, u);
}

// ---------------------------------------------------------------------------
// W_pre for the MFMA offset conv: bf16 [m=96][kpad], k = tap*CIN + ci.
// ---------------------------------------------------------------------------
template <int CIN>
__global__ __launch_bounds__(256) void make_wpre_kernel(
    const float* __restrict__ w, unsigned short* __restrict__ Wp)
{
    constexpr int NCHUNK = (CIN == 32) ? 27 : 14;
    constexpr int KPAD = NCHUNK * 32;
    const int i = blockIdx.x * 256 + threadIdx.x;
    if (i >= 96 * KPAD) return;
    const int m = i / KPAD;
    const int kg = i % KPAD;
    const int tap = kg / CIN, ci = kg % CIN;
    float val = 0.f;
    if (m < 81 && tap < 27) val = w[m * (CIN * 27) + ci * 27 + tap];
    Wp[i] = (unsigned short)bf16rne(val);
}

// Weight transpose for scalar deform: wt[co][ci][tap] -> wT[tap][ci][co].
__global__ __launch_bounds__(256) void transpose_w_kernel(
    const float* __restrict__ wt, float* __restrict__ wT, int COUTN, int CIN)
{
    const int i = blockIdx.x * 256 + threadIdx.x;
    const int total = COUTN * CIN * 27;
    if (i >= total) return;
    const int co = i / (CIN * 27);
    const int r = i % (CIN * 27);
    const int ci = r / 27;
    const int tap = r % 27;
    wT[(tap * CIN + ci) * COUTN + co] = wt[i];
}

// ---------------------------------------------------------------------------
// conv_off chunk loader: 16 strided global loads + bf16 pack for K-chunk c.
// Optional inline BN+ReLU (layer-2 reads pre-BN y).
// ---------------------------------------------------------------------------
template <int CIN, bool BN>
__device__ __forceinline__ void conv_off_load(
    const float* __restrict__ x, const float* __restrict__ sc,
    const float* __restrict__ sh, int sd, int shh, int sww, int skh, int c,
    unsigned int pk[8])
{
    const int kg0 = c * 32 + skh * 16;
    const int tap = kg0 / CIN;
    if (tap < 27) {
        const int dz = tap / 9 - 1;
        const int dy = (tap / 3) % 3 - 1;
        const int dx = tap % 3 - 1;
        const int zd = sd + dz, zh = shh + dy, zw = sww + dx;
        const bool ok = ((unsigned)zd < 48u) & ((unsigned)zh < 48u)
                      & ((unsigned)zw < 48u);
        const int gbase = (zd * DD + zh) * DD + zw;
        const int ci0 = kg0 % CIN;
        const float* xb = x + ci0 * NV + gbase;
#pragma unroll
        for (int p = 0; p < 8; ++p) {
            float f0 = ok ? xb[(2 * p) * NV] : 0.f;
            float f1 = ok ? xb[(2 * p + 1) * NV] : 0.f;
            if (BN) {
                f0 = fmaxf(f0 * sc[ci0 + 2 * p] + sh[ci0 + 2 * p], 0.f);
                f1 = fmaxf(f1 * sc[ci0 + 2 * p + 1] + sh[ci0 + 2 * p + 1], 0.f);
                if (!ok) { f0 = 0.f; f1 = 0.f; }
            }
            pk[p] = bf16rne(f0) | (bf16rne(f1) << 16);
        }
    } else {
#pragma unroll
        for (int p = 0; p < 8; ++p) pk[p] = 0u;
    }
}

// ---------------------------------------------------------------------------
// Offset conv as MFMA GEMM (verified since R6; R12 register prefetch).
// Epilogue writes packed AoS offsets off4[tap][v] = {od,oh,ow,pad} h16.
// ---------------------------------------------------------------------------
template <int CIN, bool BN>
__global__ __launch_bounds__(256) void conv_off_mfma_kernel(
    const float* __restrict__ x, const unsigned short* __restrict__ Wp,
    const float* __restrict__ bias, const float* __restrict__ sc,
    const float* __restrict__ sh, unsigned short* __restrict__ off4)
{
    constexpr int NCHUNK = (CIN == 32) ? 27 : 14;
    constexpr int KPAD = NCHUNK * 32;
    __shared__ unsigned int lds[16 * 128];   // 8 KB

    const int t = threadIdx.x;
    const int bxs = (blockIdx.x & 7) * (NV / 128 / 8) + (blockIdx.x >> 3); // XCD swizzle
    const int v0 = bxs * 128;

    const int sn = t >> 1;
    const int skh = t & 1;
    const int sv = v0 + sn;
    const int sd = sv / HW;
    const int shh = (sv / DD) % DD;
    const int sww = sv % DD;

    const int wv = t >> 6;
    const int l = t & 63;
    const int lg = l >> 4;
    const int ln = l & 15;

    const int bw0 = (((2 * wv) * 16 + ln) + 8 * lg) & 127;
    const int bw1 = (((2 * wv + 1) * 16 + ln) + 8 * lg) & 127;
    const int abase = ln * KPAD + lg * 8;

    f32x4 acc[6][2];
#pragma unroll
    for (int r = 0; r < 6; ++r)
#pragma unroll
        for (int nt = 0; nt < 2; ++nt)
            acc[r][nt] = (f32x4){0.f, 0.f, 0.f, 0.f};

    unsigned int pk[8];
    conv_off_load<CIN, BN>(x, sc, sh, sd, shh, sww, skh, 0, pk);

    for (int c = 0; c < NCHUNK; ++c) {
        __syncthreads();   // previous chunk's LDS reads done
#pragma unroll
        for (int p = 0; p < 8; ++p) {
            const int word = (skh * 8 + p) * 128
                           + ((sn + 16 * skh + 8 * (p >> 2)) & 127);
            lds[word] = pk[p];
        }
        __syncthreads();

        // prefetch next chunk into registers (overlaps the MFMAs below)
        unsigned int nk[8];
        if (c + 1 < NCHUNK) {
            conv_off_load<CIN, BN>(x, sc, sh, sd, shh, sww, skh, c + 1, nk);
        } else {
#pragma unroll
            for (int p = 0; p < 8; ++p) nk[p] = 0u;
        }

        const unsigned short* wp = Wp + c * 32 + abase;
#pragma unroll
        for (int r = 0; r < 6; ++r) {
            const bf16x8 a = *(const bf16x8*)(wp + r * 16 * KPAD);
#pragma unroll
            for (int nt = 0; nt < 2; ++nt) {
                const int bw = nt ? bw1 : bw0;
                const int w0 = (int)lds[(4 * lg + 0) * 128 + bw];
                const int w1 = (int)lds[(4 * lg + 1) * 128 + bw];
                const int w2 = (int)lds[(4 * lg + 2) * 128 + bw];
                const int w3 = (int)lds[(4 * lg + 3) * 128 + bw];
                const i32x4 wi = {w0, w1, w2, w3};
                const bf16x8 b = __builtin_bit_cast(bf16x8, wi);
                acc[r][nt] = __builtin_amdgcn_mfma_f32_16x16x32_bf16(a, b, acc[r][nt], 0, 0, 0);
            }
        }

#pragma unroll
        for (int p = 0; p < 8; ++p) pk[p] = nk[p];
    }

    // epilogue: m = axis*27 + tap; write h16 into off4[tap*NV + col] slot axis
#pragma unroll
    for (int r = 0; r < 6; ++r) {
        const int mbase = r * 16 + lg * 4;
#pragma unroll
        for (int j = 0; j < 4; ++j) {
            const int m = mbase + j;
            if (m < 81) {
                const int axis = m / 27;
                const int tap = m - axis * 27;
#pragma unroll
                for (int nt = 0; nt < 2; ++nt) {
                    const int col = v0 + (2 * wv + nt) * 16 + ln;
                    const h16 val = (h16)(acc[r][nt][j] + bias[m]);
                    ((h16*)(off4 + ((size_t)tap * NV + col) * 4))[axis] = val;
                }
            }
        }
    }
}

// ---------------------------------------------------------------------------
// Deformable conv, LDS-tiled, fp16 channel-pair tile.
// NCHC = channels per chunk (template): L1 uses 8 (864 blocks, 18.4 KB LDS —
// grid-limited layer needs the blocks; R14-proven), L2 uses 16 (864 blocks,
// 36.9 KB LDS — halves coord/off4 redundancy; R15-proven). R15 lesson:
// NCHC=16 on L1 cut the grid to 432 blocks = 1.7/CU -> latency-bound.
// ---------------------------------------------------------------------------
template <int CIN, int NCHC, bool BN>
__global__ __launch_bounds__(256) void deform_tile_kernel(
    const float* __restrict__ x, const unsigned short* __restrict__ off4,
    const float* __restrict__ wD, const float* __restrict__ sc,
    const float* __restrict__ sh, float* __restrict__ part)
{
    __shared__ __half2 regs[NCHC / 2][REGN];

    const int t = threadIdx.x;
    const int bx = (blockIdx.x & 7) * 54 + (blockIdx.x >> 3);  // XCD swizzle (432/8=54)
    const int tilew = bx % 6;
    const int tileh = (bx / 6) % 6;
    const int tiled = bx / 36;
    const int chunk = blockIdx.y;
    const int c0 = chunk * NCHC;

    const int tz = t >> 6, ty = (t >> 3) & 7, tx = t & 7;
    const int d  = tiled * TD + tz;
    const int hh = tileh * TH + ty;
    const int ww = tilew * TW + tx;
    const int v  = (d * DD + hh) * DD + ww;

    const int dlo = tiled * TD - 2;
    const int hlo = tileh * TH - 2;
    const int wlo = tilew * TW - 2;

    // ---- stage x region: NCHC/2 channel-pairs, fp16 packed (optional BN) ----
    for (int i = t; i < (NCHC / 2) * REGN; i += 256) {
        const int p = i / REGN;
        const int r = i % REGN;
        const int rz = r / (RH * RW);
        const int rr = r % (RH * RW);
        const int ry = rr / RW, rx = rr % RW;
        const int gz = min(max(dlo + rz, 0), 47);
        const int gy = min(max(hlo + ry, 0), 47);
        const int gx = min(max(wlo + rx, 0), 47);
        const int gidx = (gz * DD + gy) * DD + gx;
        float s0 = x[(c0 + 2 * p) * NV + gidx];
        float s1 = x[(c0 + 2 * p + 1) * NV + gidx];
        if (BN) {
            s0 = fmaxf(s0 * sc[c0 + 2 * p] + sh[c0 + 2 * p], 0.f);
            s1 = fmaxf(s1 * sc[c0 + 2 * p + 1] + sh[c0 + 2 * p + 1], 0.f);
        }
        regs[p][r] = __floats2half2_rn(s0, s1);
    }
    __syncthreads();

    f32x2 acc2[16];
#pragma unroll
    for (int i = 0; i < 16; ++i) acc2[i] = (f32x2){0.f, 0.f};

    for (int k = 0; k < 27; ++k) {
        const int dz = k / 9 - 1;
        const int dy = (k / 3) % 3 - 1;
        const int dx = k % 3 - 1;

        const ushort4 o4 = ((const ushort4*)off4)[(size_t)k * NV + v];
        const float od = h16f(o4.x);
        const float oh = h16f(o4.y);
        const float ow = h16f(o4.z);

        const float pd = fminf(fmaxf((float)(d + dz) + od, 0.0f), 47.0f);
        const float ph = fminf(fmaxf((float)(hh + dy) + oh, 0.0f), 47.0f);
        const float pw = fminf(fmaxf((float)(ww + dx) + ow, 0.0f), 47.0f);

        const float d0f = floorf(pd), h0f = floorf(ph), w0f = floorf(pw);
        const float fd = pd - d0f, fh = ph - h0f, fw = pw - w0f;
        const int d0 = (int)d0f, h0 = (int)h0f, w0 = (int)w0f;

        const float gd = 1.0f - fd, gh = 1.0f - fh, gw = 1.0f - fw;
        const float c000 = gd * gh * gw, c001 = gd * gh * fw;
        const float c010 = gd * fh * gw, c011 = gd * fh * fw;
        const float c100 = fd * gh * gw, c101 = fd * gh * fw;
        const float c110 = fd * fh * gw, c111 = fd * fh * fw;

        const float* wrow = wD + (k * CIN + c0) * COUT;

        const int ld = d0 - dlo, lh = h0 - hlo, lw = w0 - wlo;
        // fixed-offset reads need ld+1/lh+1/lw+1 in range (clamp => coef 0)
        const bool inreg = (ld >= 0) & (ld <= RD - 2)
                         & (lh >= 0) & (lh <= RH - 2)
                         & (lw >= 0) & (lw <= RW - 2);

        if (inreg) {
            const int base = (ld * RH + lh) * RW + lw;
            const __half2 C000 = __float2half2_rn(c000), C001 = __float2half2_rn(c001);
            const __half2 C010 = __float2half2_rn(c010), C011 = __float2half2_rn(c011);
            const __half2 C100 = __float2half2_rn(c100), C101 = __float2half2_rn(c101);
            const __half2 C110 = __float2half2_rn(c110), C111 = __float2half2_rn(c111);
#pragma unroll
            for (int p = 0; p < NCHC / 2; ++p) {
                const __half2* xc = &regs[p][base];
                __half2 vp = __hmul2(C000, xc[0]);
                vp = __hfma2(C001, xc[1], vp);
                vp = __hfma2(C010, xc[RW], vp);
                vp = __hfma2(C011, xc[RW + 1], vp);
                vp = __hfma2(C100, xc[RH * RW], vp);
                vp = __hfma2(C101, xc[RH * RW + 1], vp);
                vp = __hfma2(C110, xc[RH * RW + RW], vp);
                vp = __hfma2(C111, xc[RH * RW + RW + 1], vp);
                const float v0 = __low2float(vp);
                const float v1 = __high2float(vp);
                const f32x2* wpe = (const f32x2*)(wrow + (2 * p) * COUT);
                const f32x2* wpo = (const f32x2*)(wrow + (2 * p + 1) * COUT);
#pragma unroll
                for (int co = 0; co < 16; ++co)
                    acc2[co] += v0 * wpe[co] + v1 * wpo[co];
            }
        } else {
            const int dst = (d0 < 47) ? 1 : 0;
            const int hst = (h0 < 47) ? 1 : 0;
            const int wst = (w0 < 47) ? 1 : 0;
            const int i000 = (d0 * DD + h0) * DD + w0;
            const int sd2 = dst ? HW : 0, sh2 = hst ? DD : 0, sw2 = wst;
#pragma unroll
            for (int ci = 0; ci < NCHC; ++ci) {
                const float* xc = x + (c0 + ci) * NV + i000;
                float q000 = xc[0],         q001 = xc[sw2];
                float q010 = xc[sh2],       q011 = xc[sh2 + sw2];
                float q100 = xc[sd2],       q101 = xc[sd2 + sw2];
                float q110 = xc[sd2 + sh2], q111 = xc[sd2 + sh2 + sw2];
                if (BN) {
                    const float a = sc[c0 + ci], b = sh[c0 + ci];
                    q000 = fmaxf(q000 * a + b, 0.f); q001 = fmaxf(q001 * a + b, 0.f);
                    q010 = fmaxf(q010 * a + b, 0.f); q011 = fmaxf(q011 * a + b, 0.f);
                    q100 = fmaxf(q100 * a + b, 0.f); q101 = fmaxf(q101 * a + b, 0.f);
                    q110 = fmaxf(q110 * a + b, 0.f); q111 = fmaxf(q111 * a + b, 0.f);
                }
                const float val = q000 * c000 + q001 * c001
                                + q010 * c010 + q011 * c011
                                + q100 * c100 + q101 * c101
                                + q110 * c110 + q111 * c111;
                const f32x2* wp2 = (const f32x2*)(wrow + ci * COUT);
#pragma unroll
                for (int co = 0; co < 16; ++co)
                    acc2[co] += val * wp2[co];
            }
        }
    }

#pragma unroll
    for (int co = 0; co < 16; ++co) {
        part[((size_t)chunk * COUT + 2 * co + 0) * NV + v] = acc2[co].x;
        part[((size_t)chunk * COUT + 2 * co + 1) * NV + v] = acc2[co].y;
    }
}

// ---------------------------------------------------------------------------
// Fused: sum NC split-K partials -> y, AND accumulate per-block BN partials.
// ---------------------------------------------------------------------------
template <int NC>
__global__ __launch_bounds__(256) void reduce_stats_kernel(
    const float* __restrict__ part, float* __restrict__ y, float* __restrict__ pbuf)
{
    const int i = blockIdx.x * 256 + threadIdx.x;   // float4 index
    const int stride = COUT * NV / 4;
    float4 a = ((const float4*)part)[i];
#pragma unroll
    for (int c = 1; c < NC; ++c) {
        const float4 b = ((const float4*)part)[i + c * stride];
        a.x += b.x; a.y += b.y; a.z += b.z; a.w += b.w;
    }
    ((float4*)y)[i] = a;

    float s  = a.x + a.y + a.z + a.w;
    float s2 = a.x * a.x + a.y * a.y + a.z * a.z + a.w * a.w;
    __shared__ float ls[256], ls2[256];
    ls[threadIdx.x] = s; ls2[threadIdx.x] = s2;
    __syncthreads();
    for (int st = 128; st > 0; st >>= 1) {
        if (threadIdx.x < st) {
            ls[threadIdx.x]  += ls[threadIdx.x + st];
            ls2[threadIdx.x] += ls2[threadIdx.x + st];
        }
        __syncthreads();
    }
    if (threadIdx.x == 0) {
        pbuf[blockIdx.x * 2 + 0] = ls[0];
        pbuf[blockIdx.x * 2 + 1] = ls2[0];
    }
}

// pbuf slot b belongs to channel b/108 (NV = 108*1024).
__global__ __launch_bounds__(64) void bn_stats_final_kernel(
    const float* __restrict__ pbuf, const float* __restrict__ gamma,
    const float* __restrict__ beta, float* __restrict__ sc, float* __restrict__ sh)
{
    const int c = threadIdx.x;
    if (c >= 32) return;
    float s = 0.0f, s2 = 0.0f;
    for (int p = 0; p < 108; ++p) {
        s  += pbuf[(c * 108 + p) * 2 + 0];
        s2 += pbuf[(c * 108 + p) * 2 + 1];
    }
    const float mu = s * (1.0f / NV);
    const float var = s2 * (1.0f / NV) - mu * mu;
    const float inv = rsqrtf(var + 1e-5f);
    sc[c] = gamma[c] * inv;
    sh[c] = beta[c] - mu * gamma[c] * inv;
}

__global__ __launch_bounds__(256) void bn_apply_kernel(
    const float* __restrict__ y, const float* __restrict__ sc,
    const float* __restrict__ sh, float* __restrict__ out)
{
    const int i = blockIdx.x * 256 + threadIdx.x;
    const int c = (i * 4) / NV;
    const float a = sc[c], b = sh[c];
    float4 t = ((const float4*)y)[i];
    t.x = fmaxf(t.x * a + b, 0.0f);
    t.y = fmaxf(t.y * a + b, 0.0f);
    t.z = fmaxf(t.z * a + b, 0.0f);
    t.w = fmaxf(t.w * a + b, 0.0f);
    ((float4*)out)[i] = t;
}

// ---------------------------------------------------------------------------
extern "C" void kernel_launch(void* const* d_in, const int* in_sizes, int n_in,
                              void* d_out, int out_size, void* d_ws, size_t ws_size,
                              hipStream_t stream) {
    (void)in_sizes; (void)n_in; (void)out_size; (void)ws_size;

    const float* x      = (const float*)d_in[0];
    const float* w_off1 = (const float*)d_in[1];
    const float* b_off1 = (const float*)d_in[2];
    const float* w1     = (const float*)d_in[3];
    const float* gamma1 = (const float*)d_in[4];
    const float* beta1  = (const float*)d_in[5];
    const float* w_off2 = (const float*)d_in[6];
    const float* b_off2 = (const float*)d_in[7];
    const float* w2     = (const float*)d_in[8];
    const float* gamma2 = (const float*)d_in[9];
    const float* beta2  = (const float*)d_in[10];

    char* ws = (char*)d_ws;
    unsigned short* off4 = (unsigned short*)ws; ws += (size_t)27 * NV * 4 * sizeof(unsigned short);
    float* y    = (float*)ws;               ws += (size_t)32 * NV * sizeof(float);
    float* y2   = (float*)ws;               ws += (size_t)32 * NV * sizeof(float);
    float* part = (float*)ws;               ws += (size_t)2 * 32 * NV * sizeof(float);
    float* sc   = (float*)ws;               ws += 32 * sizeof(float);
    float* sh   = (float*)ws;               ws += 32 * sizeof(float);
    float* pbuf = (float*)ws;               ws += 3456 * 2 * sizeof(float);
    unsigned short* Wp1 = (unsigned short*)ws; ws += (size_t)96 * 448 * sizeof(unsigned short);
    unsigned short* Wp2 = (unsigned short*)ws; ws += (size_t)96 * 864 * sizeof(unsigned short);
    float* wD1  = (float*)ws;               ws += (size_t)27 * 16 * 32 * sizeof(float);
    float* wD2  = (float*)ws;               ws += (size_t)27 * 32 * 32 * sizeof(float);

    const int nel4 = (COUT * NV) / 4 / 256;   // 3456 blocks (float4 grids)
    const int ntile = 432;                    // 12 * 6 * 6
    const int ngemm = NV / 128;               // 864

    // ---- weight prep (tiny) ----
    make_wpre_kernel<16><<<(96 * 448 + 255) / 256, 256, 0, stream>>>(w_off1, Wp1);
    make_wpre_kernel<32><<<(96 * 864 + 255) / 256, 256, 0, stream>>>(w_off2, Wp2);
    transpose_w_kernel<<<(32 * 16 * 27 + 255) / 256, 256, 0, stream>>>(w1, wD1, 32, 16);
    transpose_w_kernel<<<(32 * 32 * 27 + 255) / 256, 256, 0, stream>>>(w2, wD2, 32, 32);

    // ---- layer 1 (CIN=16: NCHC=8 -> 2 chunks, 864 blocks; R14 config) ----
    conv_off_mfma_kernel<16, false><<<ngemm, 256, 0, stream>>>(x, Wp1, b_off1, nullptr, nullptr, off4);
    deform_tile_kernel<16, 8, false><<<dim3(ntile, 2), 256, 0, stream>>>(x, off4, wD1, nullptr, nullptr, part);
    reduce_stats_kernel<2><<<nel4, 256, 0, stream>>>(part, y, pbuf);
    bn_stats_final_kernel<<<1, 64, 0, stream>>>(pbuf, gamma1, beta1, sc, sh);
    // (no bn_apply: layer-2 kernels apply BN+ReLU inline when reading y)

    // ---- layer 2 (CIN=32: NCHC=16 -> 2 chunks, 864 blocks; R15 config) ----
    conv_off_mfma_kernel<32, true><<<ngemm, 256, 0, stream>>>(y, Wp2, b_off2, sc, sh, off4);
    deform_tile_kernel<32, 16, true><<<dim3(ntile, 2), 256, 0, stream>>>(y, off4, wD2, sc, sh, part);
    reduce_stats_kernel<2><<<nel4, 256, 0, stream>>>(part, y2, pbuf);
    bn_stats_final_kernel<<<1, 64, 0, stream>>>(pbuf, gamma2, beta2, sc, sh);
    bn_apply_kernel<<<nel4, 256, 0, stream>>>(y2, sc, sh, (float*)d_out);
}